// Round 4
// baseline (750.060 us; speedup 1.0000x reference)
//
#include <hip/hip_runtime.h>
#include <hip/hip_bf16.h>

#define N_    64
#define CIN   64
#define COUT  64
#define T_    256
#define V_    25
#define K_    3
#define G_    8
#define D_    192          // K_*COUT
#define TV    6400         // T_*V_
#define P_    409600.0f    // N_*T_*V_

__device__ __forceinline__ float bf2f(unsigned short u) {
    unsigned int x = ((unsigned int)u) << 16;
    return __uint_as_float(x);
}
__device__ __forceinline__ unsigned short f2bf(float f) {
    unsigned int x = __float_as_uint(f);
    unsigned int lsb = (x >> 16) & 1u;
    x += 0x7fffu + lsb;                 // RNE (no NaN/inf here)
    return (unsigned short)(x >> 16);
}

// ---------------------------------------------------------------------------
// K0: channel Gram G[c,c'] = sum_{n,t,v} x0[c]*x0[c']  and sums S[c].
// 256 blocks; block = (n, quarter). LDS tile [p=64][c=64], row stride 68.
// ---------------------------------------------------------------------------
__global__ __launch_bounds__(256, 2) void k0_gram(const float* __restrict__ x0,
                                                  float* __restrict__ Gm,
                                                  float* __restrict__ Sv) {
    __shared__ float xs[64 * 68];
    int tid = threadIdx.x;
    int n  = blockIdx.x >> 2;
    int qt = blockIdx.x & 3;
    const float* xb = x0 + (size_t)n * CIN * TV + qt * 1600;
    int i4 = (tid & 15) * 4;
    int j4 = (tid >> 4) * 4;
    float acc[16];
#pragma unroll
    for (int r = 0; r < 16; ++r) acc[r] = 0.f;
    float sacc = 0.f;
    for (int tile = 0; tile < 25; ++tile) {
        const float* xt = xb + tile * 64;
#pragma unroll
        for (int l = 0; l < 16; ++l) {
            int idx = l * 256 + tid;
            int c = idx >> 6, p = idx & 63;
            xs[p * 68 + c] = xt[(size_t)c * TV + p];
        }
        __syncthreads();
#pragma unroll 8
        for (int p = 0; p < 64; ++p) {
            const float* row = &xs[p * 68];
            float xi0 = row[i4], xi1 = row[i4 + 1], xi2 = row[i4 + 2], xi3 = row[i4 + 3];
            float xj0 = row[j4], xj1 = row[j4 + 1], xj2 = row[j4 + 2], xj3 = row[j4 + 3];
            acc[0]  += xi0 * xj0; acc[1]  += xi0 * xj1; acc[2]  += xi0 * xj2; acc[3]  += xi0 * xj3;
            acc[4]  += xi1 * xj0; acc[5]  += xi1 * xj1; acc[6]  += xi1 * xj2; acc[7]  += xi1 * xj3;
            acc[8]  += xi2 * xj0; acc[9]  += xi2 * xj1; acc[10] += xi2 * xj2; acc[11] += xi2 * xj3;
            acc[12] += xi3 * xj0; acc[13] += xi3 * xj1; acc[14] += xi3 * xj2; acc[15] += xi3 * xj3;
        }
        if (tid < 64) {
#pragma unroll 8
            for (int p = 0; p < 64; ++p) sacc += xs[p * 68 + tid];
        }
        __syncthreads();
    }
#pragma unroll
    for (int r = 0; r < 4; ++r)
#pragma unroll
        for (int s = 0; s < 4; ++s)
            atomicAdd(&Gm[(i4 + r) * 64 + (j4 + s)], acc[r * 4 + s]);
    if (tid < 64) atomicAdd(&Sv[tid], sacc);
}

// ---------------------------------------------------------------------------
// K2 (1 block): exact BN0 stats from Gram, affine (a,b), nadj, bconst.
// ---------------------------------------------------------------------------
__global__ __launch_bounds__(256, 1) void k2_prep(const float* __restrict__ A,
                                                  const float* __restrict__ W,
                                                  const float* __restrict__ bias,
                                                  const float* __restrict__ g0,
                                                  const float* __restrict__ b0,
                                                  const float* __restrict__ Gm,
                                                  const float* __restrict__ Sv,
                                                  float* a, float* b,
                                                  float* nadj, float* bconst) {
    __shared__ float Gs[4096];
    int tid = threadIdx.x;
    for (int i = tid; i < 4096; i += 256) Gs[i] = Gm[i];
    __syncthreads();
    if (tid < D_) {
        int d = tid;
        float w[64];
        float sw = 0.f;
#pragma unroll
        for (int c = 0; c < 64; ++c) { w[c] = W[c * D_ + d]; sw += w[c] * Sv[c]; }
        float quad = 0.f;
        for (int c = 0; c < 64; ++c) {
            const float* gr = &Gs[c * 64];
            float t2 = 0.f;
#pragma unroll
            for (int cc = 0; cc < 64; ++cc) t2 += w[cc] * gr[cc];
            quad += w[c] * t2;
        }
        float bd = bias[d];
        float sum0   = sw + P_ * bd;
        float sumsq0 = quad + 2.f * bd * sw + P_ * bd * bd;
        float m   = sum0 / P_;
        float var = sumsq0 / P_ - m * m;
        float sc  = g0[d] * rsqrtf(var + 1e-5f);
        a[d] = sc;
        b[d] = b0[d] - sc * m;
    }
    // nadj[k,g,v,w] = A / (colsum + 1e-3)
    for (int idx = tid; idx < K_ * G_ * V_; idx += 256) {
        int w  = idx % V_;
        int kg = idx / V_;
        const float* Ap = A + kg * V_ * V_;
        float cs = 0.f;
        for (int v = 0; v < V_; ++v) cs += Ap[v * V_ + w];
        float inv = 1.f / (cs + 1e-3f);
        for (int v = 0; v < V_; ++v) nadj[kg * V_ * V_ + v * V_ + w] = Ap[v * V_ + w] * inv;
    }
    __syncthreads();
    // bconst[c,w] = sum_k b[k*64+c] * colsum_v nadj[k, c%8, v, w]
    for (int idx = tid; idx < COUT * V_; idx += 256) {
        int c = idx / V_, w = idx % V_, g = c & 7;
        float s = 0.f;
        for (int k = 0; k < K_; ++k) {
            float bk = b[k * COUT + c];
            const float* np_ = nadj + (k * G_ + g) * V_ * V_;
            float cs = 0.f;
            for (int v = 0; v < V_; ++v) cs += np_[v * V_ + w];
            s += bk * cs;
        }
        bconst[idx] = s;
    }
}

// ---------------------------------------------------------------------------
// K1: z[n,d,t,v] = a[d] * (sum_c x0[n,c,t,v]*W[c,d] + bias[d])   (bf16)
// launch_bounds(256,4) -> VGPR cap 128 so x[64] stays register-resident.
// ---------------------------------------------------------------------------
__global__ __launch_bounds__(256, 4) void k1_gemm(const float* __restrict__ x0,
                                                  const float* __restrict__ W,
                                                  const float* __restrict__ bias,
                                                  const float* __restrict__ a,
                                                  unsigned short* __restrict__ z) {
    const int nblk = TV / 256;                 // 25
    int n  = blockIdx.x / nblk;
    int q  = (blockIdx.x % nblk) * 256 + threadIdx.x;
    const float* xp = x0 + (size_t)n * CIN * TV + q;
    float x[CIN];
#pragma unroll
    for (int c = 0; c < CIN; ++c) x[c] = xp[(size_t)c * TV];
    unsigned short* zp = z + (size_t)n * D_ * TV + q;
#pragma unroll 1
    for (int d0 = 0; d0 < D_; d0 += 32) {
        float acc[32];
#pragma unroll
        for (int j = 0; j < 32; ++j) acc[j] = bias[d0 + j];
#pragma unroll
        for (int c = 0; c < CIN; ++c) {
            float xc = x[c];
            const float* wr = &W[c * D_ + d0];
#pragma unroll
            for (int j = 0; j < 32; ++j) acc[j] += xc * wr[j];
        }
#pragma unroll
        for (int j = 0; j < 32; ++j)
            zp[(size_t)(d0 + j) * TV] = f2bf(a[d0 + j] * acc[j]);
    }
}

// ---------------------------------------------------------------------------
// K3: x2[n,c,t,w] = bconst[c,w] + sum_{k,v} z[n,k*64+c,t,v]*nadj[k,c%8,v,w]
// block = (n,c); stage the 3 z rows into LDS (coalesced), fused BN2 stats.
// ---------------------------------------------------------------------------
__global__ __launch_bounds__(256, 2) void k3_adj(const unsigned short* __restrict__ z,
                                                 const float* __restrict__ nadj,
                                                 const float* __restrict__ bconst,
                                                 unsigned short* __restrict__ x2,
                                                 float* __restrict__ sum2,
                                                 float* __restrict__ sumsq2) {
    int n = blockIdx.x >> 6;
    int c = blockIdx.x & 63;
    int g = c & 7;
    __shared__ __align__(16) unsigned short zs[K_][TV];   // 38400 B
    __shared__ float s_nadj[K_][V_ * V_];                 //  7500 B
    __shared__ float s_bc[V_];                            //   100 B
    __shared__ float rs[256], rq[256];                    //  2048 B
    int tid = threadIdx.x;
#pragma unroll
    for (int k = 0; k < K_; ++k) {
        const uint4* src = (const uint4*)(z + ((size_t)n * D_ + k * COUT + c) * TV);
        uint4* dst = (uint4*)&zs[k][0];
        for (int i = tid; i < TV * 2 / 16; i += 256) dst[i] = src[i];
    }
    for (int idx = tid; idx < K_ * V_ * V_; idx += 256) {
        int k = idx / (V_ * V_), r = idx % (V_ * V_);
        s_nadj[k][r] = nadj[(k * G_ + g) * (V_ * V_) + r];
    }
    if (tid < V_) s_bc[tid] = bconst[c * V_ + tid];
    __syncthreads();
    int t = tid;
    float acc[V_];
#pragma unroll
    for (int w = 0; w < V_; ++w) acc[w] = s_bc[w];
#pragma unroll
    for (int k = 0; k < K_; ++k) {
        const unsigned short* zr = &zs[k][t * V_];
        float yv[V_];
#pragma unroll
        for (int v = 0; v < V_; ++v) yv[v] = bf2f(zr[v]);
#pragma unroll
        for (int v = 0; v < V_; ++v) {
            float yk = yv[v];
            const float* np_ = &s_nadj[k][v * V_];
#pragma unroll
            for (int w = 0; w < V_; ++w) acc[w] += yk * np_[w];
        }
    }
    unsigned short* xp = x2 + ((size_t)n * COUT + c) * TV + t * V_;
    float s = 0.f, sq = 0.f;
#pragma unroll
    for (int w = 0; w < V_; ++w) {
        float v = acc[w];
        s += v; sq += v * v;
        xp[w] = f2bf(v);
    }
    rs[t] = s; rq[t] = sq;
    __syncthreads();
    for (int off = 128; off > 0; off >>= 1) {
        if (t < off) { rs[t] += rs[t + off]; rq[t] += rq[t + off]; }
        __syncthreads();
    }
    if (t == 0) {
        atomicAdd(&sum2[c], rs[0]);
        atomicAdd(&sumsq2[c], rq[0]);
    }
}

// ---------------------------------------------------------------------------
// K4: out = relu(BN2(x2) + x0), f32 out.
// ---------------------------------------------------------------------------
__global__ __launch_bounds__(256) void k4_final(const unsigned short* __restrict__ x2,
                                                const float* __restrict__ x0,
                                                const float* __restrict__ g2,
                                                const float* __restrict__ b2,
                                                const float* __restrict__ sum2,
                                                const float* __restrict__ sumsq2,
                                                float* __restrict__ out) {
    const int total4 = N_ * COUT * TV / 4;
    for (int i = blockIdx.x * 256 + threadIdx.x; i < total4; i += gridDim.x * 256) {
        int c = ((i * 4) / TV) & 63;
        float m   = sum2[c] * (1.f / P_);
        float var = sumsq2[c] * (1.f / P_) - m * m;
        float sc  = g2[c] * rsqrtf(var + 1e-5f);
        float sh  = b2[c] - sc * m;
        ushort4 u = ((const ushort4*)x2)[i];
        float4  x = ((const float4*)x0)[i];
        float4 o;
        o.x = fmaxf(sc * bf2f(u.x) + sh + x.x, 0.f);
        o.y = fmaxf(sc * bf2f(u.y) + sh + x.y, 0.f);
        o.z = fmaxf(sc * bf2f(u.z) + sh + x.z, 0.f);
        o.w = fmaxf(sc * bf2f(u.w) + sh + x.w, 0.f);
        ((float4*)out)[i] = o;
    }
}

extern "C" void kernel_launch(void* const* d_in, const int* in_sizes, int n_in,
                              void* d_out, int out_size, void* d_ws, size_t ws_size,
                              hipStream_t stream) {
    const float* x0   = (const float*)d_in[0];
    const float* A    = (const float*)d_in[1];
    const float* W    = (const float*)d_in[2];
    const float* bias = (const float*)d_in[3];
    const float* g0   = (const float*)d_in[4];
    const float* b0   = (const float*)d_in[5];
    const float* g2   = (const float*)d_in[6];
    const float* b2   = (const float*)d_in[7];

    char* ws = (char*)d_ws;
    unsigned short* z  = (unsigned short*)ws;                       // 157,286,400 B
    unsigned short* x2 = (unsigned short*)(ws + 157286400ull);      //  52,428,800 B
    float* fregion = (float*)(ws + 209715200ull);
    float* Gm     = fregion;           // 4096
    float* Sv     = fregion + 4096;    // 64
    float* sum2   = fregion + 4160;    // 64
    float* sumsq2 = fregion + 4224;    // 64   -> zero 4288 floats
    float* a      = fregion + 4288;    // 192
    float* b      = a + 192;           // 192
    float* nadj   = b + 192;           // 15000
    float* bconst = nadj + 15000;      // 1600

    hipMemsetAsync(fregion, 0, 4288 * sizeof(float), stream);
    k0_gram<<<256, 256, 0, stream>>>(x0, Gm, Sv);
    k2_prep<<<1, 256, 0, stream>>>(A, W, bias, g0, b0, Gm, Sv, a, b, nadj, bconst);
    k1_gemm<<<N_ * (TV / 256), 256, 0, stream>>>(x0, W, bias, a, z);
    k3_adj<<<N_ * COUT, 256, 0, stream>>>(z, nadj, bconst, x2, sum2, sumsq2);
    k4_final<<<2048, 256, 0, stream>>>(x2, x0, g2, b2, sum2, sumsq2,
                                       (float*)d_out);
}

// Round 5
// 648.118 us; speedup vs baseline: 1.1573x; 1.1573x over previous
//
#include <hip/hip_runtime.h>
#include <hip/hip_bf16.h>

#define N_    64
#define CIN   64
#define COUT  64
#define T_    256
#define V_    25
#define K_    3
#define G_    8
#define D_    192          // K_*COUT
#define TV    6400         // T_*V_
#define P_    409600.0f    // N_*T_*V_

__device__ __forceinline__ float bf2f(unsigned short u) {
    unsigned int x = ((unsigned int)u) << 16;
    return __uint_as_float(x);
}
__device__ __forceinline__ unsigned short f2bf(float f) {
    unsigned int x = __float_as_uint(f);
    unsigned int lsb = (x >> 16) & 1u;
    x += 0x7fffu + lsb;                 // RNE (no NaN/inf here)
    return (unsigned short)(x >> 16);
}

// ---------------------------------------------------------------------------
// K0: channel Gram G[c,c'] and channel sums S[c] over all (n,t,v).
// ---------------------------------------------------------------------------
__global__ __launch_bounds__(256, 2) void k0_gram(const float* __restrict__ x0,
                                                  float* __restrict__ Gm,
                                                  float* __restrict__ Sv) {
    __shared__ float xs[64 * 68];
    int tid = threadIdx.x;
    int n  = blockIdx.x >> 2;
    int qt = blockIdx.x & 3;
    const float* xb = x0 + (size_t)n * CIN * TV + qt * 1600;
    int i4 = (tid & 15) * 4;
    int j4 = (tid >> 4) * 4;
    float acc[16];
#pragma unroll
    for (int r = 0; r < 16; ++r) acc[r] = 0.f;
    float sacc = 0.f;
    for (int tile = 0; tile < 25; ++tile) {
        const float* xt = xb + tile * 64;
#pragma unroll
        for (int l = 0; l < 16; ++l) {
            int idx = l * 256 + tid;
            int c = idx >> 6, p = idx & 63;
            xs[p * 68 + c] = xt[(size_t)c * TV + p];
        }
        __syncthreads();
#pragma unroll 8
        for (int p = 0; p < 64; ++p) {
            const float* row = &xs[p * 68];
            float xi0 = row[i4], xi1 = row[i4 + 1], xi2 = row[i4 + 2], xi3 = row[i4 + 3];
            float xj0 = row[j4], xj1 = row[j4 + 1], xj2 = row[j4 + 2], xj3 = row[j4 + 3];
            acc[0]  += xi0 * xj0; acc[1]  += xi0 * xj1; acc[2]  += xi0 * xj2; acc[3]  += xi0 * xj3;
            acc[4]  += xi1 * xj0; acc[5]  += xi1 * xj1; acc[6]  += xi1 * xj2; acc[7]  += xi1 * xj3;
            acc[8]  += xi2 * xj0; acc[9]  += xi2 * xj1; acc[10] += xi2 * xj2; acc[11] += xi2 * xj3;
            acc[12] += xi3 * xj0; acc[13] += xi3 * xj1; acc[14] += xi3 * xj2; acc[15] += xi3 * xj3;
        }
        if (tid < 64) {
#pragma unroll 8
            for (int p = 0; p < 64; ++p) sacc += xs[p * 68 + tid];
        }
        __syncthreads();
    }
#pragma unroll
    for (int r = 0; r < 4; ++r)
#pragma unroll
        for (int s = 0; s < 4; ++s)
            atomicAdd(&Gm[(i4 + r) * 64 + (j4 + s)], acc[r * 4 + s]);
    if (tid < 64) atomicAdd(&Sv[tid], sacc);
}

// ---------------------------------------------------------------------------
// K1: z[n,d,t,v] = sum_c x0[n,c,t,v]*W[c,d] + bias[d]   (UNscaled y, bf16)
// acc[64] forces VGPR allocation above 64; W scalarized (uniform index).
// ---------------------------------------------------------------------------
__global__ __launch_bounds__(256, 4) void k1_gemm(const float* __restrict__ x0,
                                                  const float* __restrict__ W,
                                                  const float* __restrict__ bias,
                                                  unsigned short* __restrict__ z) {
    const int nblk = TV / 256;                 // 25
    int n  = blockIdx.x / nblk;
    int q  = (blockIdx.x % nblk) * 256 + threadIdx.x;
    const float* xp = x0 + (size_t)n * CIN * TV + q;
    unsigned short* zp = z + (size_t)n * D_ * TV + q;
#pragma unroll 1
    for (int d0 = 0; d0 < D_; d0 += 64) {
        float acc[64];
#pragma unroll
        for (int j = 0; j < 64; ++j) acc[j] = bias[d0 + j];
#pragma unroll 1
        for (int cc = 0; cc < 4; ++cc) {
            float x[16];
#pragma unroll
            for (int i = 0; i < 16; ++i) x[i] = xp[(size_t)(cc * 16 + i) * TV];
#pragma unroll
            for (int i = 0; i < 16; ++i) {
                const float* wr = &W[(cc * 16 + i) * D_ + d0];
                float xi = x[i];
#pragma unroll
                for (int j = 0; j < 64; ++j) acc[j] = fmaf(xi, wr[j], acc[j]);
            }
        }
#pragma unroll
        for (int j = 0; j < 64; ++j) zp[(size_t)(d0 + j) * TV] = f2bf(acc[j]);
    }
}

// ---------------------------------------------------------------------------
// K2 (1 block): exact BN0 stats from Gram, affine (a,b), nadj, bconst.
// ---------------------------------------------------------------------------
__global__ __launch_bounds__(256, 1) void k2_prep(const float* __restrict__ A,
                                                  const float* __restrict__ W,
                                                  const float* __restrict__ bias,
                                                  const float* __restrict__ g0,
                                                  const float* __restrict__ b0,
                                                  const float* __restrict__ Gm,
                                                  const float* __restrict__ Sv,
                                                  float* a, float* b,
                                                  float* nadj, float* bconst) {
    __shared__ float Gs[4096];
    int tid = threadIdx.x;
    for (int i = tid; i < 4096; i += 256) Gs[i] = Gm[i];
    __syncthreads();
    if (tid < D_) {
        int d = tid;
        float w[64];
        float sw = 0.f;
#pragma unroll
        for (int c = 0; c < 64; ++c) { w[c] = W[c * D_ + d]; sw += w[c] * Sv[c]; }
        float quad = 0.f;
        for (int c = 0; c < 64; ++c) {
            const float* gr = &Gs[c * 64];
            float t2 = 0.f;
#pragma unroll
            for (int cc = 0; cc < 64; ++cc) t2 += w[cc] * gr[cc];
            quad += w[c] * t2;
        }
        float bd = bias[d];
        float sum0   = sw + P_ * bd;
        float sumsq0 = quad + 2.f * bd * sw + P_ * bd * bd;
        float m   = sum0 / P_;
        float var = sumsq0 / P_ - m * m;
        float sc  = g0[d] * rsqrtf(var + 1e-5f);
        a[d] = sc;
        b[d] = b0[d] - sc * m;
    }
    for (int idx = tid; idx < K_ * G_ * V_; idx += 256) {
        int w  = idx % V_;
        int kg = idx / V_;
        const float* Ap = A + kg * V_ * V_;
        float cs = 0.f;
        for (int v = 0; v < V_; ++v) cs += Ap[v * V_ + w];
        float inv = 1.f / (cs + 1e-3f);
        for (int v = 0; v < V_; ++v) nadj[kg * V_ * V_ + v * V_ + w] = Ap[v * V_ + w] * inv;
    }
    __syncthreads();
    for (int idx = tid; idx < COUT * V_; idx += 256) {
        int c = idx / V_, w = idx % V_, g = c & 7;
        float s = 0.f;
        for (int k = 0; k < K_; ++k) {
            float bk = b[k * COUT + c];
            const float* np_ = nadj + (k * G_ + g) * V_ * V_;
            float cs = 0.f;
            for (int v = 0; v < V_; ++v) cs += np_[v * V_ + w];
            s += bk * cs;
        }
        bconst[idx] = s;
    }
}

// ---------------------------------------------------------------------------
// K3: wave <-> (n,c); lane owns t = l, l+64, l+128, l+192.
// x2[n,c,t,w] = bconst[c,w] + sum_k a[k64+c] * sum_v z[n,k64+c,t,v]*nadj[k,g,v,w]
// 1 broadcast nadj LDS read feeds 4 FMA. Fused BN2 stats (wave shuffle reduce).
// ---------------------------------------------------------------------------
__global__ __launch_bounds__(256, 2) void k3_adj(const unsigned short* __restrict__ z,
                                                 const float* __restrict__ a,
                                                 const float* __restrict__ nadj,
                                                 const float* __restrict__ bconst,
                                                 unsigned short* __restrict__ x2,
                                                 float* __restrict__ sum2,
                                                 float* __restrict__ sumsq2) {
    __shared__ float s_nadj[K_][625];
    __shared__ __align__(16) unsigned short zs[4][TV];   // 4 waves x 12800 B
    int tid = threadIdx.x;
    int g   = blockIdx.x & 7;
    int pq  = blockIdx.x >> 3;          // 0..127
    int wv  = tid >> 6;
    int l   = tid & 63;
    int p   = pq * 4 + wv;              // 0..511
    int n   = p >> 3;
    int c   = (p & 7) * 8 + g;
    for (int idx = tid; idx < K_ * 625; idx += 256) {
        int k = idx / 625, r = idx % 625;
        s_nadj[k][r] = nadj[(k * 8 + g) * 625 + r];
    }
    __syncthreads();

    float acc[4][25];
#pragma unroll
    for (int w = 0; w < 25; ++w) {
        float bc = bconst[c * 25 + w];
#pragma unroll
        for (int j = 0; j < 4; ++j) acc[j][w] = bc;
    }

    uint4* zs4 = (uint4*)&zs[wv][0];
#pragma unroll 1
    for (int k = 0; k < K_; ++k) {
        int d = k * 64 + c;
        const uint4* row4 = (const uint4*)(z + ((size_t)n * D_ + d) * TV);
        // stage this wave's 12.8 KB z-row (coalesced, per-wave, no barrier needed)
        for (int e = l; e < 800; e += 64) zs4[e] = row4[e];
        float ad = a[d];
#pragma unroll 1
        for (int v = 0; v < 25; ++v) {
            float za0 = ad * bf2f(zs[wv][(l      ) * 25 + v]);
            float za1 = ad * bf2f(zs[wv][(l +  64) * 25 + v]);
            float za2 = ad * bf2f(zs[wv][(l + 128) * 25 + v]);
            float za3 = ad * bf2f(zs[wv][(l + 192) * 25 + v]);
            const float* nr = &s_nadj[k][v * 25];
#pragma unroll
            for (int w = 0; w < 25; ++w) {
                float nv = nr[w];
                acc[0][w] = fmaf(za0, nv, acc[0][w]);
                acc[1][w] = fmaf(za1, nv, acc[1][w]);
                acc[2][w] = fmaf(za2, nv, acc[2][w]);
                acc[3][w] = fmaf(za3, nv, acc[3][w]);
            }
        }
    }

    unsigned short* xp = x2 + ((size_t)n * COUT + c) * TV;
    float s = 0.f, sq = 0.f;
#pragma unroll
    for (int j = 0; j < 4; ++j) {
        int t = l + 64 * j;
#pragma unroll
        for (int w = 0; w < 25; ++w) {
            float val = acc[j][w];
            s += val; sq += val * val;
            xp[t * 25 + w] = f2bf(val);
        }
    }
#pragma unroll
    for (int off = 32; off > 0; off >>= 1) {
        s  += __shfl_down(s,  off, 64);
        sq += __shfl_down(sq, off, 64);
    }
    if (l == 0) {
        atomicAdd(&sum2[c], s);
        atomicAdd(&sumsq2[c], sq);
    }
}

// ---------------------------------------------------------------------------
// K4: out = relu(BN2(x2) + x0), f32 out.
// ---------------------------------------------------------------------------
__global__ __launch_bounds__(256) void k4_final(const unsigned short* __restrict__ x2,
                                                const float* __restrict__ x0,
                                                const float* __restrict__ g2,
                                                const float* __restrict__ b2,
                                                const float* __restrict__ sum2,
                                                const float* __restrict__ sumsq2,
                                                float* __restrict__ out) {
    const int total4 = N_ * COUT * TV / 4;
    for (int i = blockIdx.x * 256 + threadIdx.x; i < total4; i += gridDim.x * 256) {
        int c = ((i * 4) / TV) & 63;
        float m   = sum2[c] * (1.f / P_);
        float var = sumsq2[c] * (1.f / P_) - m * m;
        float sc  = g2[c] * rsqrtf(var + 1e-5f);
        float sh  = b2[c] - sc * m;
        ushort4 u = ((const ushort4*)x2)[i];
        float4  x = ((const float4*)x0)[i];
        float4 o;
        o.x = fmaxf(sc * bf2f(u.x) + sh + x.x, 0.f);
        o.y = fmaxf(sc * bf2f(u.y) + sh + x.y, 0.f);
        o.z = fmaxf(sc * bf2f(u.z) + sh + x.z, 0.f);
        o.w = fmaxf(sc * bf2f(u.w) + sh + x.w, 0.f);
        ((float4*)out)[i] = o;
    }
}

extern "C" void kernel_launch(void* const* d_in, const int* in_sizes, int n_in,
                              void* d_out, int out_size, void* d_ws, size_t ws_size,
                              hipStream_t stream) {
    const float* x0   = (const float*)d_in[0];
    const float* A    = (const float*)d_in[1];
    const float* W    = (const float*)d_in[2];
    const float* bias = (const float*)d_in[3];
    const float* g0   = (const float*)d_in[4];
    const float* b0   = (const float*)d_in[5];
    const float* g2   = (const float*)d_in[6];
    const float* b2   = (const float*)d_in[7];

    char* ws = (char*)d_ws;
    unsigned short* z  = (unsigned short*)ws;                       // 157,286,400 B
    unsigned short* x2 = (unsigned short*)(ws + 157286400ull);      //  52,428,800 B
    float* fregion = (float*)(ws + 209715200ull);
    float* Gm     = fregion;           // 4096
    float* Sv     = fregion + 4096;    // 64
    float* sum2   = fregion + 4160;    // 64
    float* sumsq2 = fregion + 4224;    // 64   -> zero 4288 floats
    float* a      = fregion + 4288;    // 192
    float* b      = a + 192;           // 192
    float* nadj   = b + 192;           // 15000
    float* bconst = nadj + 15000;      // 1600

    hipMemsetAsync(fregion, 0, 4288 * sizeof(float), stream);
    k0_gram<<<256, 256, 0, stream>>>(x0, Gm, Sv);
    k1_gemm<<<N_ * (TV / 256), 256, 0, stream>>>(x0, W, bias, z);
    k2_prep<<<1, 256, 0, stream>>>(A, W, bias, g0, b0, Gm, Sv, a, b, nadj, bconst);
    k3_adj<<<1024, 256, 0, stream>>>(z, a, nadj, bconst, x2, sum2, sumsq2);
    k4_final<<<2048, 256, 0, stream>>>(x2, x0, g2, b2, sum2, sumsq2,
                                       (float*)d_out);
}

// Round 7
// 429.334 us; speedup vs baseline: 1.7470x; 1.5096x over previous
//
#include <hip/hip_runtime.h>
#include <hip/hip_bf16.h>

#define N_    64
#define CIN   64
#define COUT  64
#define T_    256
#define V_    25
#define K_    3
#define G_    8
#define D_    192          // K_*COUT
#define TV    6400         // T_*V_
#define P_    409600.0f    // N_*T_*V_

typedef __attribute__((ext_vector_type(8))) short bf16x8;   // 8 bf16 = 4 VGPRs
typedef __attribute__((ext_vector_type(4))) float f32x4;

__device__ __forceinline__ float bf2f(unsigned short u) {
    unsigned int x = ((unsigned int)u) << 16;
    return __uint_as_float(x);
}
__device__ __forceinline__ unsigned short f2bf(float f) {
    unsigned int x = __float_as_uint(f);
    unsigned int lsb = (x >> 16) & 1u;
    x += 0x7fffu + lsb;                 // RNE (no NaN/inf here)
    return (unsigned short)(x >> 16);
}

// ---------------------------------------------------------------------------
// K1 (MFMA): z[n,d,tv] = bf16( sum_c x0[n,c,tv]*W[c,d] + bias[d] )
// Wave = 64 rows (4 M-tiles of 16) x all 192 d. A in regs; B gathered from
// L2-resident W per d-tile. mfma_f32_16x16x32_bf16:
//   A: lane l -> row=l&15, k=(l>>4)*8+j ; B: k=(l>>4)*8+j, col=l&15
//   C: col=l&15, row=(l>>4)*4+reg       (m89-verified layout)
// ---------------------------------------------------------------------------
__global__ __launch_bounds__(256, 4) void k1_mfma(const float* __restrict__ x0,
                                                  const float* __restrict__ W,
                                                  const float* __restrict__ bias,
                                                  unsigned short* __restrict__ z) {
    int p0  = blockIdx.x * 256;          // 1600 blocks, never crosses n
    int n   = p0 / TV;
    int tvb = p0 % TV;
    int wv  = threadIdx.x >> 6;
    int l   = threadIdx.x & 63;
    int l15 = l & 15;
    int kg  = l >> 4;
    int wbase = tvb + wv * 64;
    const float* xn = x0 + (size_t)n * CIN * TV;

    bf16x8 afr[4][2];
#pragma unroll
    for (int m = 0; m < 4; ++m)
#pragma unroll
        for (int kk = 0; kk < 2; ++kk)
#pragma unroll
            for (int j = 0; j < 8; ++j) {
                int c = kk * 32 + kg * 8 + j;
                afr[m][kk][j] = (short)f2bf(xn[(size_t)c * TV + wbase + m * 16 + l15]);
            }

    unsigned short* zn = z + (size_t)n * D_ * TV;
#pragma unroll 1
    for (int dt = 0; dt < 12; ++dt) {
        int dcol = dt * 16 + l15;
        bf16x8 bfr[2];
#pragma unroll
        for (int kk = 0; kk < 2; ++kk)
#pragma unroll
            for (int j = 0; j < 8; ++j) {
                int c = kk * 32 + kg * 8 + j;
                bfr[kk][j] = (short)f2bf(W[c * D_ + dcol]);
            }
        float bv = bias[dcol];
        f32x4 acc[4];
#pragma unroll
        for (int m = 0; m < 4; ++m) {
            acc[m][0] = bv; acc[m][1] = bv; acc[m][2] = bv; acc[m][3] = bv;
        }
#pragma unroll
        for (int m = 0; m < 4; ++m) {
            acc[m] = __builtin_amdgcn_mfma_f32_16x16x32_bf16(afr[m][0], bfr[0], acc[m], 0, 0, 0);
            acc[m] = __builtin_amdgcn_mfma_f32_16x16x32_bf16(afr[m][1], bfr[1], acc[m], 0, 0, 0);
        }
        unsigned short* zp = zn + (size_t)dcol * TV;
#pragma unroll
        for (int m = 0; m < 4; ++m) {
            int tv0 = wbase + m * 16 + kg * 4;
            uint2 pk;
            pk.x = (unsigned int)f2bf(acc[m][0]) | ((unsigned int)f2bf(acc[m][1]) << 16);
            pk.y = (unsigned int)f2bf(acc[m][2]) | ((unsigned int)f2bf(acc[m][3]) << 16);
            *(uint2*)(zp + tv0) = pk;
        }
    }
}

// ---------------------------------------------------------------------------
// K1b: per-channel (192) sum / sumsq of z.
// ---------------------------------------------------------------------------
__global__ __launch_bounds__(256) void k1b_stats(const unsigned short* __restrict__ z,
                                                 float* __restrict__ sum0,
                                                 float* __restrict__ sumsq0) {
    int d    = blockIdx.x;      // 0..191
    int slab = blockIdx.y;      // 0..7
    float s = 0.f, sq = 0.f;
    for (int n = slab * 8; n < slab * 8 + 8; ++n) {
        const ushort4* zp = (const ushort4*)(z + ((size_t)n * D_ + d) * TV);
        for (int i = threadIdx.x; i < TV / 4; i += 256) {
            ushort4 u = zp[i];
            float a0 = bf2f(u.x), a1 = bf2f(u.y), a2 = bf2f(u.z), a3 = bf2f(u.w);
            s  += (a0 + a1) + (a2 + a3);
            sq += (a0 * a0 + a1 * a1) + (a2 * a2 + a3 * a3);
        }
    }
    __shared__ float rs[256], rq[256];
    rs[threadIdx.x] = s; rq[threadIdx.x] = sq;
    __syncthreads();
    for (int off = 128; off > 0; off >>= 1) {
        if (threadIdx.x < off) {
            rs[threadIdx.x] += rs[threadIdx.x + off];
            rq[threadIdx.x] += rq[threadIdx.x + off];
        }
        __syncthreads();
    }
    if (threadIdx.x == 0) {
        atomicAdd(&sum0[d], rs[0]);
        atomicAdd(&sumsq0[d], rq[0]);
    }
}

// ---------------------------------------------------------------------------
// K2 (1 block, light): BN0 affine (a,b), nadj, bconst.
// ---------------------------------------------------------------------------
__global__ __launch_bounds__(256, 1) void k2_prep(const float* __restrict__ A,
                                                  const float* __restrict__ g0,
                                                  const float* __restrict__ b0,
                                                  const float* __restrict__ sum0,
                                                  const float* __restrict__ sumsq0,
                                                  float* a, float* b,
                                                  float* nadj, float* bconst) {
    int tid = threadIdx.x;
    if (tid < D_) {
        float m   = sum0[tid] / P_;
        float var = sumsq0[tid] / P_ - m * m;
        float sc  = g0[tid] * rsqrtf(var + 1e-5f);
        a[tid] = sc;
        b[tid] = b0[tid] - sc * m;
    }
    for (int idx = tid; idx < K_ * G_ * V_; idx += 256) {
        int w  = idx % V_;
        int kg = idx / V_;
        const float* Ap = A + kg * V_ * V_;
        float cs = 0.f;
        for (int v = 0; v < V_; ++v) cs += Ap[v * V_ + w];
        float inv = 1.f / (cs + 1e-3f);
        for (int v = 0; v < V_; ++v) nadj[kg * V_ * V_ + v * V_ + w] = Ap[v * V_ + w] * inv;
    }
    __syncthreads();
    for (int idx = tid; idx < COUT * V_; idx += 256) {
        int c = idx / V_, w = idx % V_, g = c & 7;
        float s = 0.f;
        for (int k = 0; k < K_; ++k) {
            float bk = b[k * COUT + c];
            const float* np_ = nadj + (k * G_ + g) * V_ * V_;
            float cs = 0.f;
            for (int v = 0; v < V_; ++v) cs += np_[v * V_ + w];
            s += bk * cs;
        }
        bconst[idx] = s;
    }
}

// ---------------------------------------------------------------------------
// K3: wave <-> (n,c); lane owns t = l, l+64, l+128, l+192.
// x2 = bconst + sum_k a[k64+c] * sum_v z*nadj. Fused BN2 stats.
// ---------------------------------------------------------------------------
__global__ __launch_bounds__(256, 2) void k3_adj(const unsigned short* __restrict__ z,
                                                 const float* __restrict__ a,
                                                 const float* __restrict__ nadj,
                                                 const float* __restrict__ bconst,
                                                 unsigned short* __restrict__ x2,
                                                 float* __restrict__ sum2,
                                                 float* __restrict__ sumsq2) {
    __shared__ float s_nadj[K_][625];
    __shared__ __align__(16) unsigned short zs[4][TV];
    int tid = threadIdx.x;
    int g   = blockIdx.x & 7;
    int pq  = blockIdx.x >> 3;
    int wv  = tid >> 6;
    int l   = tid & 63;
    int p   = pq * 4 + wv;
    int n   = p >> 3;
    int c   = (p & 7) * 8 + g;
    for (int idx = tid; idx < K_ * 625; idx += 256) {
        int k = idx / 625, r = idx % 625;
        s_nadj[k][r] = nadj[(k * 8 + g) * 625 + r];
    }
    __syncthreads();

    float acc[4][25];
#pragma unroll
    for (int w = 0; w < 25; ++w) {
        float bc = bconst[c * 25 + w];
#pragma unroll
        for (int j = 0; j < 4; ++j) acc[j][w] = bc;
    }

    uint4* zs4 = (uint4*)&zs[wv][0];
#pragma unroll 1
    for (int k = 0; k < K_; ++k) {
        int d = k * 64 + c;
        const uint4* row4 = (const uint4*)(z + ((size_t)n * D_ + d) * TV);
        for (int e = l; e < 800; e += 64) zs4[e] = row4[e];
        float ad = a[d];
#pragma unroll 1
        for (int v = 0; v < 25; ++v) {
            float za0 = ad * bf2f(zs[wv][(l      ) * 25 + v]);
            float za1 = ad * bf2f(zs[wv][(l +  64) * 25 + v]);
            float za2 = ad * bf2f(zs[wv][(l + 128) * 25 + v]);
            float za3 = ad * bf2f(zs[wv][(l + 192) * 25 + v]);
            const float* nr = &s_nadj[k][v * 25];
#pragma unroll
            for (int w = 0; w < 25; ++w) {
                float nv = nr[w];
                acc[0][w] = fmaf(za0, nv, acc[0][w]);
                acc[1][w] = fmaf(za1, nv, acc[1][w]);
                acc[2][w] = fmaf(za2, nv, acc[2][w]);
                acc[3][w] = fmaf(za3, nv, acc[3][w]);
            }
        }
    }

    unsigned short* xp = x2 + ((size_t)n * COUT + c) * TV;
    float s = 0.f, sq = 0.f;
#pragma unroll
    for (int j = 0; j < 4; ++j) {
        int t = l + 64 * j;
#pragma unroll
        for (int w = 0; w < 25; ++w) {
            float val = acc[j][w];
            s += val; sq += val * val;
            xp[t * 25 + w] = f2bf(val);
        }
    }
#pragma unroll
    for (int off = 32; off > 0; off >>= 1) {
        s  += __shfl_down(s,  off, 64);
        sq += __shfl_down(sq, off, 64);
    }
    if (l == 0) {
        atomicAdd(&sum2[c], s);
        atomicAdd(&sumsq2[c], sq);
    }
}

// ---------------------------------------------------------------------------
// K4: out = relu(BN2(x2) + x0), f32 out.
// ---------------------------------------------------------------------------
__global__ __launch_bounds__(256) void k4_final(const unsigned short* __restrict__ x2,
                                                const float* __restrict__ x0,
                                                const float* __restrict__ g2,
                                                const float* __restrict__ b2,
                                                const float* __restrict__ sum2,
                                                const float* __restrict__ sumsq2,
                                                float* __restrict__ out) {
    const int total4 = N_ * COUT * TV / 4;
    for (int i = blockIdx.x * 256 + threadIdx.x; i < total4; i += gridDim.x * 256) {
        int c = ((i * 4) / TV) & 63;
        float m   = sum2[c] * (1.f / P_);
        float var = sumsq2[c] * (1.f / P_) - m * m;
        float sc  = g2[c] * rsqrtf(var + 1e-5f);
        float sh  = b2[c] - sc * m;
        ushort4 u = ((const ushort4*)x2)[i];
        float4  x = ((const float4*)x0)[i];
        float4 o;
        o.x = fmaxf(sc * bf2f(u.x) + sh + x.x, 0.f);
        o.y = fmaxf(sc * bf2f(u.y) + sh + x.y, 0.f);
        o.z = fmaxf(sc * bf2f(u.z) + sh + x.z, 0.f);
        o.w = fmaxf(sc * bf2f(u.w) + sh + x.w, 0.f);
        ((float4*)out)[i] = o;
    }
}

extern "C" void kernel_launch(void* const* d_in, const int* in_sizes, int n_in,
                              void* d_out, int out_size, void* d_ws, size_t ws_size,
                              hipStream_t stream) {
    const float* x0   = (const float*)d_in[0];
    const float* A    = (const float*)d_in[1];
    const float* W    = (const float*)d_in[2];
    const float* bias = (const float*)d_in[3];
    const float* g0   = (const float*)d_in[4];
    const float* b0   = (const float*)d_in[5];
    const float* g2   = (const float*)d_in[6];
    const float* b2   = (const float*)d_in[7];

    char* ws = (char*)d_ws;
    unsigned short* z  = (unsigned short*)ws;                       // 157,286,400 B
    unsigned short* x2 = (unsigned short*)(ws + 157286400ull);      //  52,428,800 B
    float* fregion = (float*)(ws + 209715200ull);
    float* sum0   = fregion;           // 192
    float* sumsq0 = fregion + 192;     // 192
    float* sum2   = fregion + 384;     // 64
    float* sumsq2 = fregion + 448;     // 64  -> zero 512 floats
    float* a      = fregion + 512;     // 192
    float* b      = a + 192;           // 192
    float* nadj   = b + 192;           // 15000
    float* bconst = nadj + 15000;      // 1600

    hipMemsetAsync(fregion, 0, 512 * sizeof(float), stream);
    k1_mfma<<<1600, 256, 0, stream>>>(x0, W, bias, z);
    k1b_stats<<<dim3(D_, 8), 256, 0, stream>>>(z, sum0, sumsq0);
    k2_prep<<<1, 256, 0, stream>>>(A, g0, b0, sum0, sumsq0, a, b, nadj, bconst);
    k3_adj<<<1024, 256, 0, stream>>>(z, a, nadj, bconst, x2, sum2, sumsq2);
    k4_final<<<2048, 256, 0, stream>>>(x2, x0, g2, b2, sum2, sumsq2,
                                       (float*)d_out);
}

// Round 8
// 395.918 us; speedup vs baseline: 1.8945x; 1.0844x over previous
//
#include <hip/hip_runtime.h>
#include <hip/hip_bf16.h>

#define N_    64
#define CIN   64
#define COUT  64
#define T_    256
#define V_    25
#define K_    3
#define G_    8
#define D_    192          // K_*COUT
#define TV    6400         // T_*V_
#define P_    409600.0f    // N_*T_*V_
#define NBLK1 1600         // k1 grid

typedef __attribute__((ext_vector_type(8))) short bf16x8;   // 8 bf16 = 4 VGPRs
typedef __attribute__((ext_vector_type(4))) float f32x4;

__device__ __forceinline__ float bf2f(unsigned short u) {
    unsigned int x = ((unsigned int)u) << 16;
    return __uint_as_float(x);
}
__device__ __forceinline__ unsigned short f2bf(float f) {
    unsigned int x = __float_as_uint(f);
    unsigned int lsb = (x >> 16) & 1u;
    x += 0x7fffu + lsb;                 // RNE (no NaN/inf here)
    return (unsigned short)(x >> 16);
}

// ---------------------------------------------------------------------------
// K1 (MFMA): z[n,d,tv] = bf16( sum_c x0[n,c,tv]*W[c,d] + bias[d] )
// Wave = 64 tv rows x 192 d. C-tiles bounced through padded LDS so global
// stores are 4x128B contiguous segments per instruction (was 16x32B).
// Fused BN0 partial stats (f32, pre-rounding) -> part[block][384].
// ---------------------------------------------------------------------------
__global__ __launch_bounds__(256, 4) void k1_mfma(const float* __restrict__ x0,
                                                  const float* __restrict__ W,
                                                  const float* __restrict__ bias,
                                                  unsigned short* __restrict__ z,
                                                  float* __restrict__ part) {
    __shared__ unsigned short zb[4][16 * 68];      // per-wave bounce, row stride 68
    __shared__ float ps[4][12][16], pq[4][12][16];
    int p0  = blockIdx.x * 256;          // 1600 blocks, never crosses n
    int n   = p0 / TV;
    int tvb = p0 % TV;
    int wv  = threadIdx.x >> 6;
    int l   = threadIdx.x & 63;
    int l15 = l & 15;
    int kg  = l >> 4;
    int wbase = tvb + wv * 64;
    const float* xn = x0 + (size_t)n * CIN * TV;

    bf16x8 afr[4][2];
#pragma unroll
    for (int m = 0; m < 4; ++m)
#pragma unroll
        for (int kk = 0; kk < 2; ++kk)
#pragma unroll
            for (int j = 0; j < 8; ++j) {
                int c = kk * 32 + kg * 8 + j;
                afr[m][kk][j] = (short)f2bf(xn[(size_t)c * TV + wbase + m * 16 + l15]);
            }

    unsigned short* zn = z + (size_t)n * D_ * TV;
    unsigned short* zw = &zb[wv][0];
#pragma unroll 1
    for (int dt = 0; dt < 12; ++dt) {
        int dcol = dt * 16 + l15;
        bf16x8 bfr[2];
#pragma unroll
        for (int kk = 0; kk < 2; ++kk)
#pragma unroll
            for (int j = 0; j < 8; ++j) {
                int c = kk * 32 + kg * 8 + j;
                bfr[kk][j] = (short)f2bf(W[c * D_ + dcol]);
            }
        float bv = bias[dcol];
        f32x4 acc[4];
#pragma unroll
        for (int m = 0; m < 4; ++m) {
            acc[m][0] = bv; acc[m][1] = bv; acc[m][2] = bv; acc[m][3] = bv;
        }
#pragma unroll
        for (int m = 0; m < 4; ++m) {
            acc[m] = __builtin_amdgcn_mfma_f32_16x16x32_bf16(afr[m][0], bfr[0], acc[m], 0, 0, 0);
            acc[m] = __builtin_amdgcn_mfma_f32_16x16x32_bf16(afr[m][1], bfr[1], acc[m], 0, 0, 0);
        }
        // fused BN0 stats on f32 values (lane covers 16 tv of column dcol)
        float s = 0.f, sq = 0.f;
#pragma unroll
        for (int m = 0; m < 4; ++m)
#pragma unroll
            for (int r = 0; r < 4; ++r) {
                float v = acc[m][r];
                s += v; sq += v * v;
            }
        s  += __shfl_xor(s, 16, 64);  s  += __shfl_xor(s, 32, 64);
        sq += __shfl_xor(sq, 16, 64); sq += __shfl_xor(sq, 32, 64);
        if (kg == 0) { ps[wv][dt][l15] = s; pq[wv][dt][l15] = sq; }
        // bounce C tile through LDS: write [d=l15][tv], read row-linear
#pragma unroll
        for (int m = 0; m < 4; ++m) {
            uint2 pk;
            pk.x = (unsigned int)f2bf(acc[m][0]) | ((unsigned int)f2bf(acc[m][1]) << 16);
            pk.y = (unsigned int)f2bf(acc[m][2]) | ((unsigned int)f2bf(acc[m][3]) << 16);
            *(uint2*)(&zw[l15 * 68 + m * 16 + kg * 4]) = pk;
        }
#pragma unroll
        for (int i = 0; i < 4; ++i) {
            int dR  = i * 4 + kg;       // 0..15
            int tvo = l15 * 4;          // 0..60
            uint2 v = *(const uint2*)(&zw[dR * 68 + tvo]);
            *(uint2*)(zn + (size_t)(dt * 16 + dR) * TV + wbase + tvo) = v;
        }
    }
    __syncthreads();
    int tid = threadIdx.x;
    if (tid < D_) {
        int dt = tid >> 4, lo = tid & 15;
        float s = ps[0][dt][lo] + ps[1][dt][lo] + ps[2][dt][lo] + ps[3][dt][lo];
        float q = pq[0][dt][lo] + pq[1][dt][lo] + pq[2][dt][lo] + pq[3][dt][lo];
        part[(size_t)blockIdx.x * 384 + tid]        = s;
        part[(size_t)blockIdx.x * 384 + 192 + tid]  = q;
    }
}

// ---------------------------------------------------------------------------
// K1c: reduce part[1600][384] -> sum0[192], sumsq0[192].
// ---------------------------------------------------------------------------
__global__ __launch_bounds__(64) void k1c_reduce(const float* __restrict__ part,
                                                 float* __restrict__ sum0,
                                                 float* __restrict__ sumsq0) {
    int idx = blockIdx.x;           // 0..383
    int l = threadIdx.x;
    float s = 0.f;
    for (int b = l; b < NBLK1; b += 64) s += part[(size_t)b * 384 + idx];
#pragma unroll
    for (int off = 32; off > 0; off >>= 1) s += __shfl_down(s, off, 64);
    if (l == 0) {
        if (idx < D_) sum0[idx] = s;
        else          sumsq0[idx - D_] = s;
    }
}

// ---------------------------------------------------------------------------
// K2 (1 block, light): BN0 affine (a,b), nadj, bconst.
// ---------------------------------------------------------------------------
__global__ __launch_bounds__(256, 1) void k2_prep(const float* __restrict__ A,
                                                  const float* __restrict__ g0,
                                                  const float* __restrict__ b0,
                                                  const float* __restrict__ sum0,
                                                  const float* __restrict__ sumsq0,
                                                  float* a, float* b,
                                                  float* nadj, float* bconst) {
    int tid = threadIdx.x;
    if (tid < D_) {
        float m   = sum0[tid] / P_;
        float var = sumsq0[tid] / P_ - m * m;
        float sc  = g0[tid] * rsqrtf(var + 1e-5f);
        a[tid] = sc;
        b[tid] = b0[tid] - sc * m;
    }
    for (int idx = tid; idx < K_ * G_ * V_; idx += 256) {
        int w  = idx % V_;
        int kg = idx / V_;
        const float* Ap = A + kg * V_ * V_;
        float cs = 0.f;
        for (int v = 0; v < V_; ++v) cs += Ap[v * V_ + w];
        float inv = 1.f / (cs + 1e-3f);
        for (int v = 0; v < V_; ++v) nadj[kg * V_ * V_ + v * V_ + w] = Ap[v * V_ + w] * inv;
    }
    __syncthreads();
    for (int idx = tid; idx < COUT * V_; idx += 256) {
        int c = idx / V_, w = idx % V_, g = c & 7;
        float s = 0.f;
        for (int k = 0; k < K_; ++k) {
            float bk = b[k * COUT + c];
            const float* np_ = nadj + (k * G_ + g) * V_ * V_;
            float cs = 0.f;
            for (int v = 0; v < V_; ++v) cs += np_[v * V_ + w];
            s += bk * cs;
        }
        bconst[idx] = s;
    }
}

// ---------------------------------------------------------------------------
// K3: wave <-> (n,c); lane owns t = l, l+64, l+128, l+192.
// x2 = bconst + sum_k a[k64+c] * sum_v z*nadj. Fused BN2 stats.
// ---------------------------------------------------------------------------
__global__ __launch_bounds__(256, 2) void k3_adj(const unsigned short* __restrict__ z,
                                                 const float* __restrict__ a,
                                                 const float* __restrict__ nadj,
                                                 const float* __restrict__ bconst,
                                                 unsigned short* __restrict__ x2,
                                                 float* __restrict__ sum2,
                                                 float* __restrict__ sumsq2) {
    __shared__ float s_nadj[K_][625];
    __shared__ __align__(16) unsigned short zs[4][TV];
    int tid = threadIdx.x;
    int g   = blockIdx.x & 7;
    int pq  = blockIdx.x >> 3;
    int wv  = tid >> 6;
    int l   = tid & 63;
    int p   = pq * 4 + wv;
    int n   = p >> 3;
    int c   = (p & 7) * 8 + g;
    for (int idx = tid; idx < K_ * 625; idx += 256) {
        int k = idx / 625, r = idx % 625;
        s_nadj[k][r] = nadj[(k * 8 + g) * 625 + r];
    }
    __syncthreads();

    float acc[4][25];
#pragma unroll
    for (int w = 0; w < 25; ++w) {
        float bc = bconst[c * 25 + w];
#pragma unroll
        for (int j = 0; j < 4; ++j) acc[j][w] = bc;
    }

    uint4* zs4 = (uint4*)&zs[wv][0];
#pragma unroll 1
    for (int k = 0; k < K_; ++k) {
        int d = k * 64 + c;
        const uint4* row4 = (const uint4*)(z + ((size_t)n * D_ + d) * TV);
        for (int e = l; e < 800; e += 64) zs4[e] = row4[e];
        float ad = a[d];
#pragma unroll 1
        for (int v = 0; v < 25; ++v) {
            float za0 = ad * bf2f(zs[wv][(l      ) * 25 + v]);
            float za1 = ad * bf2f(zs[wv][(l +  64) * 25 + v]);
            float za2 = ad * bf2f(zs[wv][(l + 128) * 25 + v]);
            float za3 = ad * bf2f(zs[wv][(l + 192) * 25 + v]);
            const float* nr = &s_nadj[k][v * 25];
#pragma unroll
            for (int w = 0; w < 25; ++w) {
                float nv = nr[w];
                acc[0][w] = fmaf(za0, nv, acc[0][w]);
                acc[1][w] = fmaf(za1, nv, acc[1][w]);
                acc[2][w] = fmaf(za2, nv, acc[2][w]);
                acc[3][w] = fmaf(za3, nv, acc[3][w]);
            }
        }
    }

    unsigned short* xp = x2 + ((size_t)n * COUT + c) * TV;
    float s = 0.f, sq = 0.f;
#pragma unroll
    for (int j = 0; j < 4; ++j) {
        int t = l + 64 * j;
#pragma unroll
        for (int w = 0; w < 25; ++w) {
            float val = acc[j][w];
            s += val; sq += val * val;
            xp[t * 25 + w] = f2bf(val);
        }
    }
#pragma unroll
    for (int off = 32; off > 0; off >>= 1) {
        s  += __shfl_down(s,  off, 64);
        sq += __shfl_down(sq, off, 64);
    }
    if (l == 0) {
        atomicAdd(&sum2[c], s);
        atomicAdd(&sumsq2[c], sq);
    }
}

// ---------------------------------------------------------------------------
// K4: out = relu(BN2(x2) + x0), f32 out.
// ---------------------------------------------------------------------------
__global__ __launch_bounds__(256) void k4_final(const unsigned short* __restrict__ x2,
                                                const float* __restrict__ x0,
                                                const float* __restrict__ g2,
                                                const float* __restrict__ b2,
                                                const float* __restrict__ sum2,
                                                const float* __restrict__ sumsq2,
                                                float* __restrict__ out) {
    const int total4 = N_ * COUT * TV / 4;
    for (int i = blockIdx.x * 256 + threadIdx.x; i < total4; i += gridDim.x * 256) {
        int c = ((i * 4) / TV) & 63;
        float m   = sum2[c] * (1.f / P_);
        float var = sumsq2[c] * (1.f / P_) - m * m;
        float sc  = g2[c] * rsqrtf(var + 1e-5f);
        float sh  = b2[c] - sc * m;
        ushort4 u = ((const ushort4*)x2)[i];
        float4  x = ((const float4*)x0)[i];
        float4 o;
        o.x = fmaxf(sc * bf2f(u.x) + sh + x.x, 0.f);
        o.y = fmaxf(sc * bf2f(u.y) + sh + x.y, 0.f);
        o.z = fmaxf(sc * bf2f(u.z) + sh + x.z, 0.f);
        o.w = fmaxf(sc * bf2f(u.w) + sh + x.w, 0.f);
        ((float4*)out)[i] = o;
    }
}

extern "C" void kernel_launch(void* const* d_in, const int* in_sizes, int n_in,
                              void* d_out, int out_size, void* d_ws, size_t ws_size,
                              hipStream_t stream) {
    const float* x0   = (const float*)d_in[0];
    const float* A    = (const float*)d_in[1];
    const float* W    = (const float*)d_in[2];
    const float* bias = (const float*)d_in[3];
    const float* g0   = (const float*)d_in[4];
    const float* b0   = (const float*)d_in[5];
    const float* g2   = (const float*)d_in[6];
    const float* b2   = (const float*)d_in[7];

    char* ws = (char*)d_ws;
    unsigned short* z  = (unsigned short*)ws;                       // 157,286,400 B
    unsigned short* x2 = (unsigned short*)(ws + 157286400ull);      //  52,428,800 B
    float* part = (float*)x2;   // 1600*384*4 = 2.46 MB, consumed by k1c BEFORE k3 writes x2
    float* fregion = (float*)(ws + 209715200ull);
    float* sum0   = fregion;           // 192
    float* sumsq0 = fregion + 192;     // 192
    float* sum2   = fregion + 384;     // 64
    float* sumsq2 = fregion + 448;     // 64  -> zero 512 floats
    float* a      = fregion + 512;     // 192
    float* b      = a + 192;           // 192
    float* nadj   = b + 192;           // 15000
    float* bconst = nadj + 15000;      // 1600

    hipMemsetAsync(fregion, 0, 512 * sizeof(float), stream);
    k1_mfma<<<NBLK1, 256, 0, stream>>>(x0, W, bias, z, part);
    k1c_reduce<<<384, 64, 0, stream>>>(part, sum0, sumsq0);
    k2_prep<<<1, 256, 0, stream>>>(A, g0, b0, sum0, sumsq0, a, b, nadj, bconst);
    k3_adj<<<1024, 256, 0, stream>>>(z, a, nadj, bconst, x2, sum2, sumsq2);
    k4_final<<<2048, 256, 0, stream>>>(x2, x0, g2, b2, sum2, sumsq2,
                                       (float*)d_out);
}